// Round 2
// baseline (287.785 us; speedup 1.0000x reference)
//
#include <hip/hip_runtime.h>
#include <hip/hip_bf16.h>

#define B_ 4
#define T_ 8192
#define D_ 512
#define H_ 512
#define CHUNK 128
#define NCHUNK (T_ / CHUNK)   // 64

typedef __attribute__((ext_vector_type(8))) short short8;
typedef __attribute__((ext_vector_type(4))) float floatx4;

__device__ __forceinline__ unsigned short f2bf(float f) {
    union { float f; unsigned int u; } v; v.f = f;
    unsigned int u = v.u;
    u += 0x7fffu + ((u >> 16) & 1u);   // round-to-nearest-even
    return (unsigned short)(u >> 16);
}
__device__ __forceinline__ float bf2f(unsigned short s) {
    union { unsigned int u; float f; } v; v.u = ((unsigned int)s) << 16;
    return v.f;
}

// ---------------------------------------------------------------------------
// Kernel 1: dual bf16-MFMA GEMM (x·Wz^T, x·Wh^T) + activation epilogue.
//   c = sigmoid(-kz)         -> bf16 in ws
//   d = sigmoid(kz) * g(hp)  -> f32 in d_out (scratch; overwritten by h later)
// Tile: BM=128 x BN=64 (per weight matrix), BK=32, 4 waves (2x2), each wave
// 64x32, 4x2 mfma tiles x 2 matrices = 16 MFMA / K-iter.
// ---------------------------------------------------------------------------
#define BM 128
#define BN 64
#define BK 32
#define LDST 40   // padded LDS row stride (bf16 elems): 80 B -> 16B-aligned frags, <=2-way bank conflict (free)

__global__ __launch_bounds__(256, 2)
void gemm_act(const float* __restrict__ x,
              const float* __restrict__ Wh, const float* __restrict__ bh,
              const float* __restrict__ Wz, const float* __restrict__ bz,
              unsigned short* __restrict__ c_bf,
              float* __restrict__ d_val)
{
    __shared__ unsigned short lds_a [BM * LDST];
    __shared__ unsigned short lds_bz[BN * LDST];
    __shared__ unsigned short lds_bh[BN * LDST];

    const int tid  = threadIdx.x;
    const int nblk = blockIdx.x & 7;    // 512/64 = 8 n-blocks (fast-varying for L2 reuse of A)
    const int mblk = blockIdx.x >> 3;   // 256 m-blocks
    const int m0 = mblk * BM;
    const int n0 = nblk * BN;

    const int lane = tid & 63;
    const int wave = tid >> 6;
    const int wm   = (wave >> 1) * 64;
    const int wn   = (wave & 1) * 32;
    const int l15  = lane & 15;
    const int quad = lane >> 4;

    floatx4 acc_z[4][2], acc_h[4][2];
    #pragma unroll
    for (int i = 0; i < 4; ++i)
        #pragma unroll
        for (int j = 0; j < 2; ++j) {
            acc_z[i][j] = (floatx4)0.0f;
            acc_h[i][j] = (floatx4)0.0f;
        }

    for (int kt = 0; kt < D_ / BK; ++kt) {
        const int kb = kt * BK;
        __syncthreads();   // previous iteration's LDS reads done
        // --- stage A tile: 128x32 f32 -> bf16.  4096 f32 = 1024 float4; 4/thread
        #pragma unroll
        for (int i = 0; i < 4; ++i) {
            int slot = tid + i * 256;
            int row = slot >> 3, c4 = slot & 7;
            float4 v = *(const float4*)(x + (size_t)(m0 + row) * D_ + kb + c4 * 4);
            ushort4 w; w.x = f2bf(v.x); w.y = f2bf(v.y); w.z = f2bf(v.z); w.w = f2bf(v.w);
            *(ushort4*)&lds_a[row * LDST + c4 * 4] = w;
        }
        // --- stage both B tiles: 64x32 f32 each; 512 float4 each; 2/thread each
        #pragma unroll
        for (int i = 0; i < 2; ++i) {
            int slot = tid + i * 256;
            int row = slot >> 3, c4 = slot & 7;
            {
                float4 v = *(const float4*)(Wz + (size_t)(n0 + row) * D_ + kb + c4 * 4);
                ushort4 w; w.x = f2bf(v.x); w.y = f2bf(v.y); w.z = f2bf(v.z); w.w = f2bf(v.w);
                *(ushort4*)&lds_bz[row * LDST + c4 * 4] = w;
            }
            {
                float4 v = *(const float4*)(Wh + (size_t)(n0 + row) * D_ + kb + c4 * 4);
                ushort4 w; w.x = f2bf(v.x); w.y = f2bf(v.y); w.z = f2bf(v.z); w.w = f2bf(v.w);
                *(ushort4*)&lds_bh[row * LDST + c4 * 4] = w;
            }
        }
        __syncthreads();

        short8 af[4], bzf[2], bhf[2];
        #pragma unroll
        for (int mt = 0; mt < 4; ++mt)
            af[mt] = *(const short8*)&lds_a[(wm + mt * 16 + l15) * LDST + quad * 8];
        #pragma unroll
        for (int nt = 0; nt < 2; ++nt) {
            bzf[nt] = *(const short8*)&lds_bz[(wn + nt * 16 + l15) * LDST + quad * 8];
            bhf[nt] = *(const short8*)&lds_bh[(wn + nt * 16 + l15) * LDST + quad * 8];
        }
        #pragma unroll
        for (int mt = 0; mt < 4; ++mt)
            #pragma unroll
            for (int nt = 0; nt < 2; ++nt) {
                acc_z[mt][nt] = __builtin_amdgcn_mfma_f32_16x16x32_bf16(af[mt], bzf[nt], acc_z[mt][nt], 0, 0, 0);
                acc_h[mt][nt] = __builtin_amdgcn_mfma_f32_16x16x32_bf16(af[mt], bhf[nt], acc_h[mt][nt], 0, 0, 0);
            }
    }

    // --- epilogue: C/D layout col = lane&15 (n), row = quad*4 + reg (m)
    #pragma unroll
    for (int nt = 0; nt < 2; ++nt) {
        const int gn = n0 + wn + nt * 16 + l15;
        const float bzv = bz[gn];
        const float bhv = bh[gn];
        #pragma unroll
        for (int mt = 0; mt < 4; ++mt) {
            #pragma unroll
            for (int r = 0; r < 4; ++r) {
                const int gm = m0 + wm + mt * 16 + quad * 4 + r;
                float kz = acc_z[mt][nt][r] + bzv;
                float hp = acc_h[mt][nt][r] + bhv;
                float z  = 1.0f / (1.0f + __expf(-kz));   // sigmoid(kz)
                float cc = 1.0f / (1.0f + __expf(kz));    // 1 - z
                float g  = (hp >= 0.0f) ? (hp + 0.5f) : (1.0f / (1.0f + __expf(-hp)));
                size_t idx = (size_t)gm * H_ + gn;
                c_bf[idx]  = f2bf(cc);
                d_val[idx] = z * g;
            }
        }
    }
}

// ---------------------------------------------------------------------------
// Kernel 2: per-chunk aggregates (C = prod c, D = chunk applied to 0)
// grid = B*NCHUNK blocks x H threads; lane==h -> coalesced
// ---------------------------------------------------------------------------
__global__ void chunk_scan(const unsigned short* __restrict__ c_bf,
                           const float* __restrict__ d_val,
                           float* __restrict__ Cagg,
                           float* __restrict__ Dagg)
{
    const int h = threadIdx.x;
    const int j = blockIdx.x % NCHUNK;
    const int b = blockIdx.x / NCHUNK;
    size_t base = ((size_t)b * T_ + (size_t)j * CHUNK) * H_ + h;
    float C = 1.0f, Dv = 0.0f;
    #pragma unroll 8
    for (int t = 0; t < CHUNK; ++t) {
        float cc = bf2f(c_bf[base + (size_t)t * H_]);
        float dd = d_val[base + (size_t)t * H_];
        Dv = fmaf(cc, Dv, dd);
        C *= cc;
    }
    size_t o = ((size_t)b * NCHUNK + j) * H_ + h;
    Cagg[o] = C;
    Dagg[o] = Dv;
}

// ---------------------------------------------------------------------------
// Kernel 3: sequential inter-chunk scan (B*H lanes x NCHUNK steps)
// ---------------------------------------------------------------------------
__global__ void interchunk(const float* __restrict__ h_prev,
                           const float* __restrict__ Cagg,
                           const float* __restrict__ Dagg,
                           float* __restrict__ Hstart)
{
    const int h = threadIdx.x;
    const int b = blockIdx.x;
    float hs = h_prev[(size_t)b * H_ + h];
    #pragma unroll 16
    for (int j = 0; j < NCHUNK; ++j) {
        size_t o = ((size_t)b * NCHUNK + j) * H_ + h;
        Hstart[o] = hs;
        hs = fmaf(Cagg[o], hs, Dagg[o]);
    }
}

// ---------------------------------------------------------------------------
// Kernel 4: apply chunk-start state, write h in-place over d (same buffer)
// ---------------------------------------------------------------------------
__global__ void apply_scan(const unsigned short* __restrict__ c_bf,
                           const float* __restrict__ Hstart,
                           float* __restrict__ io)
{
    const int h = threadIdx.x;
    const int j = blockIdx.x % NCHUNK;
    const int b = blockIdx.x / NCHUNK;
    float hs = Hstart[((size_t)b * NCHUNK + j) * H_ + h];
    size_t base = ((size_t)b * T_ + (size_t)j * CHUNK) * H_ + h;
    #pragma unroll 8
    for (int t = 0; t < CHUNK; ++t) {
        size_t o = base + (size_t)t * H_;
        float cc = bf2f(c_bf[o]);
        float dd = io[o];            // d value written by gemm_act
        hs = fmaf(cc, hs, dd);
        io[o] = hs;                  // overwrite with h (same thread, read-then-write)
    }
}

// ---------------------------------------------------------------------------
extern "C" void kernel_launch(void* const* d_in, const int* in_sizes, int n_in,
                              void* d_out, int out_size, void* d_ws, size_t ws_size,
                              hipStream_t stream)
{
    const float* x      = (const float*)d_in[0];
    const float* h_prev = (const float*)d_in[1];
    const float* W_h    = (const float*)d_in[2];
    const float* b_h    = (const float*)d_in[3];
    const float* W_z    = (const float*)d_in[4];
    const float* b_z    = (const float*)d_in[5];
    float* out = (float*)d_out;

    char* ws = (char*)d_ws;
    unsigned short* c_bf = (unsigned short*)ws;                       // B*T*H bf16  (32 MB)
    size_t c_bytes = (size_t)B_ * T_ * H_ * sizeof(unsigned short);
    float* Cagg   = (float*)(ws + c_bytes);                           // B*NC*H f32 (0.5 MB)
    float* Dagg   = Cagg + (size_t)B_ * NCHUNK * H_;
    float* Hstart = Dagg + (size_t)B_ * NCHUNK * H_;

    // 1) dual GEMM + activations
    gemm_act<<<dim3((B_ * T_ / BM) * (H_ / BN)), dim3(256), 0, stream>>>(
        x, W_h, b_h, W_z, b_z, c_bf, out);
    // 2) chunk-local aggregates
    chunk_scan<<<dim3(B_ * NCHUNK), dim3(H_), 0, stream>>>(c_bf, out, Cagg, Dagg);
    // 3) inter-chunk sequential scan
    interchunk<<<dim3(B_), dim3(H_), 0, stream>>>(h_prev, Cagg, Dagg, Hstart);
    // 4) final apply, h written in-place over d
    apply_scan<<<dim3(B_ * NCHUNK), dim3(H_), 0, stream>>>(c_bf, Hstart, out);
}

// Round 3
// 264.519 us; speedup vs baseline: 1.0880x; 1.0880x over previous
//
#include <hip/hip_runtime.h>
#include <hip/hip_bf16.h>
#include <stdint.h>

#define B_ 4
#define T_ 8192
#define D_ 512
#define H_ 512
#define M_ (B_ * T_)          // 32768 rows
#define NF 1024               // fused N: [0,512)=kz (Wz), [512,1024)=hp (Wh)
#define CHUNK 64
#define NCHUNK (T_ / CHUNK)   // 128

typedef __attribute__((ext_vector_type(8))) short short8;
typedef __attribute__((ext_vector_type(4))) float floatx4;

__device__ __forceinline__ unsigned short f2bf(float f) {
    union { float f; unsigned int u; } v; v.f = f;
    unsigned int u = v.u;
    u += 0x7fffu + ((u >> 16) & 1u);   // RNE
    return (unsigned short)(u >> 16);
}
__device__ __forceinline__ float2 bf2x2(unsigned int u) {
    union { unsigned int i; float f; } a, b;
    a.i = u << 16;            // low ushort = elem 0
    b.i = u & 0xffff0000u;    // high ushort = elem 1
    return make_float2(a.f, b.f);
}

// ---------------------------------------------------------------------------
// f32 -> bf16 converter (vectorized, memory-bound)
// ---------------------------------------------------------------------------
__global__ void conv_f32_bf16(const float* __restrict__ src,
                              unsigned short* __restrict__ dst, int n4) {
    int i = blockIdx.x * blockDim.x + threadIdx.x;
    if (i >= n4) return;
    float4 v = ((const float4*)src)[i];
    ushort4 w;
    w.x = f2bf(v.x); w.y = f2bf(v.y); w.z = f2bf(v.z); w.w = f2bf(v.w);
    ((ushort4*)dst)[i] = w;
}

// ---------------------------------------------------------------------------
// GEMM: pre[M][1024] = x[M][512] · Wf[1024][512]^T + (bias in epilogue)
// m97 structure: 128x128 tile, BK=32, 4 waves (2x2, 64x64 each),
// global_load_lds width=16, XOR-swizzled unpadded LDS (k-part ^= row&3).
// Output stored as bf16 raw preactivations.
// ---------------------------------------------------------------------------
__global__ __launch_bounds__(256)
void gemm_pre(const unsigned short* __restrict__ xbf,
              const unsigned short* __restrict__ Wf,
              const float* __restrict__ bz, const float* __restrict__ bh,
              unsigned short* __restrict__ pre)
{
    __shared__ unsigned short lA[128 * 32];   // 8 KB, row-major [row][k], no pad
    __shared__ unsigned short lB[128 * 32];   // 8 KB

    const int tid  = threadIdx.x;
    const int lane = tid & 63;
    const int wave = tid >> 6;
    const int nblk = blockIdx.x & 7;          // 8 n-blocks
    const int mblk = blockIdx.x >> 3;         // 256 m-blocks
    const int m0 = mblk * 128;
    const int n0 = nblk * 128;
    const int wm = (wave >> 1) * 64;
    const int wn = (wave & 1) * 64;
    const int l15  = lane & 15;
    const int quad = lane >> 4;

    // staging geometry: each wave stages 1 KB chunks (16 rows); lane l covers
    // row = chunk*16 + l/4, 16B k-part slot = l&3. Data placed at slot s comes
    // from global k-part (s ^ (row&3))  -> frag read inverts the swizzle.
    const int srow = lane >> 2;
    const int sp   = lane & 3;

    floatx4 acc[4][4];
    #pragma unroll
    for (int i = 0; i < 4; ++i)
        #pragma unroll
        for (int j = 0; j < 4; ++j) acc[i][j] = (floatx4)0.0f;

    for (int kt = 0; kt < D_ / 32; ++kt) {
        const int kb = kt * 32;
        __syncthreads();   // prior ds_reads done before overwrite
        #pragma unroll
        for (int r = 0; r < 2; ++r) {
            const int chunk = r * 4 + wave;          // 0..7
            const int row   = chunk * 16 + srow;     // 0..127
            const int kp    = sp ^ (row & 3);        // swizzled source k-part
            __builtin_amdgcn_global_load_lds(
                (const __attribute__((address_space(1))) unsigned int*)
                    (xbf + (size_t)(m0 + row) * D_ + kb + kp * 8),
                (__attribute__((address_space(3))) unsigned int*)(lA + chunk * 512),
                16, 0, 0);
            __builtin_amdgcn_global_load_lds(
                (const __attribute__((address_space(1))) unsigned int*)
                    (Wf + (size_t)(n0 + row) * D_ + kb + kp * 8),
                (__attribute__((address_space(3))) unsigned int*)(lB + chunk * 512),
                16, 0, 0);
        }
        __syncthreads();   // compiler emits vmcnt(0) drain here

        short8 af[4], bf[4];
        #pragma unroll
        for (int i = 0; i < 4; ++i) {
            const int ra = wm + i * 16 + l15;
            af[i] = *(const short8*)&lA[ra * 32 + ((quad ^ (ra & 3)) * 8)];
            const int rb = wn + i * 16 + l15;
            bf[i] = *(const short8*)&lB[rb * 32 + ((quad ^ (rb & 3)) * 8)];
        }
        #pragma unroll
        for (int i = 0; i < 4; ++i)
            #pragma unroll
            for (int j = 0; j < 4; ++j)
                acc[i][j] = __builtin_amdgcn_mfma_f32_16x16x32_bf16(af[i], bf[j], acc[i][j], 0, 0, 0);
    }

    // epilogue: C/D layout col(n)=lane&15, row(m)=quad*4+reg
    const float* bias = (n0 < 512) ? (bz + n0) : (bh + (n0 - 512));
    #pragma unroll
    for (int j = 0; j < 4; ++j) {
        const int nloc = wn + j * 16 + l15;
        const int gn = n0 + nloc;
        const float bv = bias[nloc];
        #pragma unroll
        for (int i = 0; i < 4; ++i) {
            #pragma unroll
            for (int r = 0; r < 4; ++r) {
                const int gm = m0 + wm + i * 16 + quad * 4 + r;
                pre[(size_t)gm * NF + gn] = f2bf(acc[i][j][r] + bv);
            }
        }
    }
}

// ---------------------------------------------------------------------------
// activation helpers: c = sigmoid(-kz), d = (1-c) * g(hp)
// ---------------------------------------------------------------------------
__device__ __forceinline__ void act_cd(float kz, float hp, float& c, float& d) {
    c = 1.0f / (1.0f + __expf(kz));       // sigmoid(-kz) = 1 - z
    float z = 1.0f - c;
    float g = (hp >= 0.0f) ? (hp + 0.5f) : (1.0f / (1.0f + __expf(-hp)));
    d = z * g;
}

// ---------------------------------------------------------------------------
// chunk aggregates: per (b, chunk j, h): C = prod c, D = scan of d from 0
// 256 threads x 2 h each; reads kz/hp streams from pre, recomputes activations
// ---------------------------------------------------------------------------
__global__ __launch_bounds__(256)
void chunk_scan(const unsigned short* __restrict__ pre,
                float* __restrict__ Cagg, float* __restrict__ Dagg)
{
    const int t2 = threadIdx.x;                  // h pair = 2*t2
    const int j = blockIdx.x & (NCHUNK - 1);
    const int b = blockIdx.x >> 7;               // NCHUNK = 128
    const unsigned short* base = pre + ((size_t)(b * T_ + j * CHUNK)) * NF + 2 * t2;
    float C0 = 1.0f, C1 = 1.0f, D0 = 0.0f, D1 = 0.0f;
    #pragma unroll 4
    for (int t = 0; t < CHUNK; ++t) {
        unsigned int kz2 = *(const unsigned int*)(base + (size_t)t * NF);
        unsigned int hp2 = *(const unsigned int*)(base + (size_t)t * NF + 512);
        float2 kz = bf2x2(kz2), hp = bf2x2(hp2);
        float c0, d0, c1, d1;
        act_cd(kz.x, hp.x, c0, d0);
        act_cd(kz.y, hp.y, c1, d1);
        D0 = fmaf(c0, D0, d0);  C0 *= c0;
        D1 = fmaf(c1, D1, d1);  C1 *= c1;
    }
    size_t o = ((size_t)(b * NCHUNK + j)) * H_ + 2 * t2;
    *(float2*)&Cagg[o] = make_float2(C0, C1);
    *(float2*)&Dagg[o] = make_float2(D0, D1);
}

// ---------------------------------------------------------------------------
// inter-chunk sequential scan: B blocks x H threads
// ---------------------------------------------------------------------------
__global__ void interchunk(const float* __restrict__ h_prev,
                           const float* __restrict__ Cagg,
                           const float* __restrict__ Dagg,
                           float* __restrict__ Hstart)
{
    const int h = threadIdx.x;
    const int b = blockIdx.x;
    float hs = h_prev[(size_t)b * H_ + h];
    #pragma unroll 8
    for (int j = 0; j < NCHUNK; ++j) {
        size_t o = ((size_t)(b * NCHUNK + j)) * H_ + h;
        Hstart[o] = hs;
        hs = fmaf(Cagg[o], hs, Dagg[o]);
    }
}

// ---------------------------------------------------------------------------
// final apply: recompute c,d from pre, scan within chunk, write h (f32)
// ---------------------------------------------------------------------------
__global__ __launch_bounds__(256)
void apply_scan(const unsigned short* __restrict__ pre,
                const float* __restrict__ Hstart,
                float* __restrict__ out)
{
    const int t2 = threadIdx.x;
    const int j = blockIdx.x & (NCHUNK - 1);
    const int b = blockIdx.x >> 7;
    float2 hs = *(const float2*)&Hstart[((size_t)(b * NCHUNK + j)) * H_ + 2 * t2];
    float hs0 = hs.x, hs1 = hs.y;
    const unsigned short* base = pre + ((size_t)(b * T_ + j * CHUNK)) * NF + 2 * t2;
    float* ob = out + ((size_t)(b * T_ + j * CHUNK)) * H_ + 2 * t2;
    #pragma unroll 4
    for (int t = 0; t < CHUNK; ++t) {
        unsigned int kz2 = *(const unsigned int*)(base + (size_t)t * NF);
        unsigned int hp2 = *(const unsigned int*)(base + (size_t)t * NF + 512);
        float2 kz = bf2x2(kz2), hp = bf2x2(hp2);
        float c0, d0, c1, d1;
        act_cd(kz.x, hp.x, c0, d0);
        act_cd(kz.y, hp.y, c1, d1);
        hs0 = fmaf(c0, hs0, d0);
        hs1 = fmaf(c1, hs1, d1);
        *(float2*)(ob + (size_t)t * H_) = make_float2(hs0, hs1);
    }
}

// ---------------------------------------------------------------------------
extern "C" void kernel_launch(void* const* d_in, const int* in_sizes, int n_in,
                              void* d_out, int out_size, void* d_ws, size_t ws_size,
                              hipStream_t stream)
{
    const float* x      = (const float*)d_in[0];
    const float* h_prev = (const float*)d_in[1];
    const float* W_h    = (const float*)d_in[2];
    const float* b_h    = (const float*)d_in[3];
    const float* W_z    = (const float*)d_in[4];
    const float* b_z    = (const float*)d_in[5];
    float* out = (float*)d_out;

    // xbf lives in d_out (dead until apply_scan overwrites all of it)
    unsigned short* xbf = (unsigned short*)d_out;               // M*512 bf16 = 33.5 MB (< 67 MB out)

    char* ws = (char*)d_ws;
    unsigned short* pre = (unsigned short*)ws;                  // M*1024 bf16 = 67.1 MB
    size_t pre_bytes = (size_t)M_ * NF * sizeof(unsigned short);
    unsigned short* Wf = (unsigned short*)(ws + pre_bytes);     // 1024*512 bf16 = 1 MB
    size_t wf_bytes = (size_t)NF * D_ * sizeof(unsigned short);
    float* Cagg   = (float*)(ws + pre_bytes + wf_bytes);        // 1 MB each
    float* Dagg   = Cagg + (size_t)B_ * NCHUNK * H_;
    float* Hstart = Dagg + (size_t)B_ * NCHUNK * H_;

    // 0) convert inputs to bf16
    {
        int n4 = M_ * D_ / 4;
        conv_f32_bf16<<<dim3((n4 + 255) / 256), dim3(256), 0, stream>>>(x, xbf, n4);
        int w4 = H_ * D_ / 4;
        conv_f32_bf16<<<dim3((w4 + 255) / 256), dim3(256), 0, stream>>>(W_z, Wf, w4);
        conv_f32_bf16<<<dim3((w4 + 255) / 256), dim3(256), 0, stream>>>(W_h, Wf + (size_t)H_ * D_, w4);
    }
    // 1) fused GEMM -> raw preactivations (bf16)
    gemm_pre<<<dim3((M_ / 128) * (NF / 128)), dim3(256), 0, stream>>>(
        xbf, Wf, b_z, b_h, pre);
    // 2) chunk-local aggregates (activations recomputed on the fly)
    chunk_scan<<<dim3(B_ * NCHUNK), dim3(256), 0, stream>>>(pre, Cagg, Dagg);
    // 3) inter-chunk sequential scan
    interchunk<<<dim3(B_), dim3(H_), 0, stream>>>(h_prev, Cagg, Dagg, Hstart);
    // 4) final apply, h (f32) -> d_out (overwrites xbf scratch)
    apply_scan<<<dim3(B_ * NCHUNK), dim3(256), 0, stream>>>(pre, Hstart, out);
}